// Round 5
// baseline (1017.959 us; speedup 1.0000x reference)
//
#include <hip/hip_runtime.h>

// RNN-T Joint network, MI355X (gfx950)
// B=8 T=200 U=100 D=512 J=512 V=1024
// out[b,t,u,v] = sum_j tanh(enc_proj[b,t,j] + dec_proj[b,u,j]) * W_out[v,j] + b_out[v]
//
// joint_kernel v4: barrier-free, occupancy-doubled.
//  - BM=64: A-strip 64 rows x 512 K bf16, transposed As[g][row] = 64 KB LDS
//    -> 2 blocks/CU (4 waves/SIMD) for latency hiding.  tanh once per element.
//  - B (W_out bf16, transposed Wbt[g][col]) read L2->VGPR directly, coalesced;
//    no LDS staging, no main-loop barriers.
//  - 8 waves, each owns 64 rows x 64 cols per pass; 2 passes of 512 cols.
//  - __launch_bounds__(512,4) caps VGPR at 128 so both blocks stay resident.

#define B_ 8
#define T_ 200
#define U_ 100
#define J_ 512
#define V_ 1024
#define M2_ (B_ * T_ * U_)   // 160000

typedef __attribute__((ext_vector_type(4))) float float4v;
typedef __attribute__((ext_vector_type(8))) short short8;
typedef __attribute__((ext_vector_type(4))) float f32x4;

#define DEV static __device__ __forceinline__

DEV unsigned short f2bf(float f) {
  unsigned int u = __float_as_uint(f);
  u += 0x7FFFu + ((u >> 16) & 1u);
  return (unsigned short)(u >> 16);
}

DEV short8 pack8(float4v a, float4v b) {
  short8 r;
  r[0] = (short)f2bf(a[0]); r[1] = (short)f2bf(a[1]);
  r[2] = (short)f2bf(a[2]); r[3] = (short)f2bf(a[3]);
  r[4] = (short)f2bf(b[0]); r[5] = (short)f2bf(b[1]);
  r[6] = (short)f2bf(b[2]); r[7] = (short)f2bf(b[3]);
  return r;
}

DEV float fast_tanh(float x) {
  float t = __expf(2.0f * x);
  float r = __builtin_amdgcn_rcpf(t + 1.0f);
  return __builtin_fmaf(-2.0f, r, 1.0f);
}

// ---------------------------------------------------------------------------
// Kernel 1: W_out fp32 [1024][512] -> bf16 TRANSPOSED Wbt[g][col][8]
// (g = K-granule of 8 bf16, 64 granules; col = vocab 0..1023)
// ---------------------------------------------------------------------------
__global__ __launch_bounds__(256) void convert_wout(
    const float* __restrict__ W, unsigned short* __restrict__ Wbt) {
  int i = blockIdx.x * 256 + threadIdx.x;   // 65536 threads
  int col = i & 1023;
  int g = i >> 10;                           // 0..63
  const float* p = W + (size_t)col * 512 + g * 8;
  float4v a = *(const float4v*)p;
  float4v b = *(const float4v*)(p + 4);
  *(short8*)(Wbt + (size_t)g * 8192 + col * 8) = pack8(a, b);
}

// ---------------------------------------------------------------------------
// Kernel 2: projections via bf16 MFMA (unchanged).
// blocks 0..199: enc (1600x512 @ W_enc^T + b_enc); 200..303: dec (800x512).
// ---------------------------------------------------------------------------
#define SWZ64(base, row, kb) ((base) + ((row) << 7) + ((((kb) ^ ((row) & 7))) << 4))

__global__ __launch_bounds__(256) void proj_kernel(
    const float* __restrict__ enc_out, const float* __restrict__ dec_out,
    const float* __restrict__ W_enc, const float* __restrict__ b_enc,
    const float* __restrict__ W_dec,
    float* __restrict__ enc_proj, float* __restrict__ dec_proj) {
  __shared__ char lds[16384];
  char* Albs = lds;
  char* Blbs = lds + 8192;

  int bid = blockIdx.x;
  bool is_enc = bid < 200;
  const float* srcA;
  const float* Wsrc;
  float* dst;
  int Mrows, bm, bn;
  if (is_enc) {
    bm = bid >> 3; bn = bid & 7;
    srcA = enc_out; Wsrc = W_enc; dst = enc_proj; Mrows = 1600;
  } else {
    int q = bid - 200;
    bm = q >> 3; bn = q & 7;
    srcA = dec_out; Wsrc = W_dec; dst = dec_proj; Mrows = 800;
  }

  int t = threadIdx.x;
  int l = t & 63;
  int w = t >> 6;
  int wrow = w >> 1, wcol = w & 1;

  f32x4 acc[2][2] = {};

  for (int k0 = 0; k0 < 512; k0 += 64) {
#pragma unroll
    for (int i = 0; i < 2; ++i) {
      int g = t + i * 256;
      int row = g >> 3, kb = g & 7;
      int arow = bm * 64 + row;
      if (arow >= Mrows) arow = Mrows - 1;
      const float* pa = srcA + (size_t)arow * 512 + k0 + kb * 8;
      *(short8*)SWZ64(Albs, row, kb) =
          pack8(*(const float4v*)pa, *(const float4v*)(pa + 4));
      const float* pb = Wsrc + (size_t)(bn * 64 + row) * 512 + k0 + kb * 8;
      *(short8*)SWZ64(Blbs, row, kb) =
          pack8(*(const float4v*)pb, *(const float4v*)(pb + 4));
    }
    __syncthreads();
#pragma unroll
    for (int h = 0; h < 2; ++h) {
      int kb = h * 4 + (l >> 4);
      short8 af[2], bfv[2];
#pragma unroll
      for (int m = 0; m < 2; ++m) {
        int row = wrow * 32 + m * 16 + (l & 15);
        af[m] = *(const short8*)SWZ64(Albs, row, kb);
      }
#pragma unroll
      for (int n = 0; n < 2; ++n) {
        int row = wcol * 32 + n * 16 + (l & 15);
        bfv[n] = *(const short8*)SWZ64(Blbs, row, kb);
      }
#pragma unroll
      for (int m = 0; m < 2; ++m)
#pragma unroll
        for (int n = 0; n < 2; ++n)
          acc[m][n] = __builtin_amdgcn_mfma_f32_16x16x32_bf16(
              af[m], bfv[n], acc[m][n], 0, 0, 0);
    }
    __syncthreads();
  }

#pragma unroll
  for (int n = 0; n < 2; ++n) {
    int col = bn * 64 + wcol * 32 + n * 16 + (l & 15);
    float bias = is_enc ? b_enc[col] : 0.0f;
#pragma unroll
    for (int m = 0; m < 2; ++m) {
#pragma unroll
      for (int j = 0; j < 4; ++j) {
        int gr = bm * 64 + wrow * 32 + m * 16 + (l >> 4) * 4 + j;
        if (gr < Mrows) dst[(size_t)gr * 512 + col] = acc[m][n][j] + bias;
      }
    }
  }
}

// ---------------------------------------------------------------------------
// Kernel 3: fused tanh-joint GEMM, BM=64, 2 blocks/CU.
// Grid 2500 blocks, 512 threads (8 waves; wave w owns cols w*64 of each pass).
// ---------------------------------------------------------------------------
__global__ __launch_bounds__(512, 4) void joint_kernel(
    const float* __restrict__ enc_proj, const float* __restrict__ dec_proj,
    const unsigned short* __restrict__ Wbt, const float* __restrict__ b_out,
    float* __restrict__ out) {
  // A-strip transposed: As[g][row], g in [0,64), row in [0,64).
  // byte addr = g*1024 + row*16.  64 KB.
  __shared__ char As[65536];

  int bm = blockIdx.x;                   // 0..2499
  int t = threadIdx.x;
  int l = t & 63;
  int w = t >> 6;                        // 0..7 -> 64-col group within pass
  int lr = l & 15;
  int lg = l >> 4;

  // ---- A-strip generation: tanh(enc+dec) -> bf16 -> As[g][row], ONCE
  {
    int row = t & 63;
    int gbase = t >> 6;                  // 0..7
    int gr = bm * 64 + row;
    int b_ = gr / 20000;                 // T*U
    int rem = gr - b_ * 20000;
    int u_ = rem % 100;
    int erow = gr / 100;                 // b*T + t
    int drow = b_ * 100 + u_;            // b*U + u
    const float* pe_base = enc_proj + (size_t)erow * 512;
    const float* pd_base = dec_proj + (size_t)drow * 512;
#pragma unroll
    for (int i = 0; i < 8; ++i) {
      int g = gbase + i * 8;             // granule 0..63
      const float* pe = pe_base + g * 8;
      const float* pd = pd_base + g * 8;
      float4v e0 = *(const float4v*)pe;
      float4v e1 = *(const float4v*)(pe + 4);
      float4v d0 = *(const float4v*)pd;
      float4v d1 = *(const float4v*)(pd + 4);
      float4v j0, j1;
#pragma unroll
      for (int q = 0; q < 4; ++q) {
        j0[q] = fast_tanh(e0[q] + d0[q]);
        j1[q] = fast_tanh(e1[q] + d1[q]);
      }
      *(short8*)(As + g * 1024 + row * 16) = pack8(j0, j1);
    }
  }
  __syncthreads();   // the ONLY block-wide barrier

  // ---- 2 N-passes of 512 cols; wave tile 64 rows x 64 cols (4m x 4n)
  for (int np = 0; np < 2; ++np) {
    int colbase = np * 512 + w * 64;
    float bias[4];
#pragma unroll
    for (int n = 0; n < 4; ++n) bias[n] = b_out[colbase + n * 16 + lr];

    f32x4 acc[4][4];
#pragma unroll
    for (int m = 0; m < 4; ++m)
#pragma unroll
      for (int n = 0; n < 4; ++n)
        acc[m][n] = (f32x4){0.f, 0.f, 0.f, 0.f};

    for (int ks = 0; ks < 8; ++ks) {
#pragma unroll
      for (int kk = 0; kk < 2; ++kk) {
        int g = ks * 8 + kk * 4 + lg;    // K-granule for this fragment
        short8 af[4], bfv[4];
#pragma unroll
        for (int n = 0; n < 4; ++n) {
          int c = colbase + n * 16 + lr;
          bfv[n] = *(const short8*)(Wbt + (size_t)g * 8192 + c * 8);
        }
#pragma unroll
        for (int m = 0; m < 4; ++m) {
          int r = m * 16 + lr;
          af[m] = *(const short8*)(As + g * 1024 + r * 16);
        }
        __builtin_amdgcn_s_setprio(1);
#pragma unroll
        for (int m = 0; m < 4; ++m)
#pragma unroll
          for (int n = 0; n < 4; ++n)
            acc[m][n] = __builtin_amdgcn_mfma_f32_16x16x32_bf16(
                af[m], bfv[n], acc[m][n], 0, 0, 0);
        __builtin_amdgcn_s_setprio(0);
      }
    }

    // ---- epilogue for this pass: + b_out, store fp32
#pragma unroll
    for (int n = 0; n < 4; ++n) {
      int col = colbase + n * 16 + lr;
#pragma unroll
      for (int m = 0; m < 4; ++m) {
        int r0 = bm * 64 + m * 16 + lg * 4;
#pragma unroll
        for (int j = 0; j < 4; ++j)
          out[(size_t)(r0 + j) * 1024 + col] = acc[m][n][j] + bias[n];
      }
    }
  }
}

// ---------------------------------------------------------------------------
extern "C" void kernel_launch(void* const* d_in, const int* in_sizes, int n_in,
                              void* d_out, int out_size, void* d_ws, size_t ws_size,
                              hipStream_t stream) {
  const float* enc_out = (const float*)d_in[0];
  const float* dec_out = (const float*)d_in[1];
  const float* W_enc   = (const float*)d_in[2];
  const float* b_enc   = (const float*)d_in[3];
  const float* W_dec   = (const float*)d_in[4];
  const float* W_out   = (const float*)d_in[5];
  const float* b_out   = (const float*)d_in[6];
  float* out = (float*)d_out;

  char* ws = (char*)d_ws;
  float* enc_proj = (float*)ws;                                    // 3276800 B
  float* dec_proj = (float*)(ws + 3276800);                        // 1638400 B
  unsigned short* Wbt = (unsigned short*)(ws + 3276800 + 1638400); // 1 MB

  hipLaunchKernelGGL(convert_wout, dim3(256), dim3(256), 0, stream, W_out, Wbt);
  hipLaunchKernelGGL(proj_kernel, dim3(304), dim3(256), 0, stream,
                     enc_out, dec_out, W_enc, b_enc, W_dec, enc_proj, dec_proj);
  hipLaunchKernelGGL(joint_kernel, dim3(M2_ / 64), dim3(512), 0, stream,
                     enc_proj, dec_proj, Wbt, b_out, out);
}